// Round 4
// baseline (2152.368 us; speedup 1.0000x reference)
//
#include <hip/hip_runtime.h>

// TruncatedHistoryAttn, round 10.
// Phase 1 (unchanged): fp32 tiled GEMM  A = H@W1 (-> ws), B2 = H@W2 (-> d_out).
// Phase 2 = round-9 + two latency cures:
//  - TWO-BATCH INTERLEAVE: grid 128; WG (g, blow) serves batches blow and
//    blow+16 (same g -> same W3 slice, wa[64] shared). Batch-1's whole step
//    runs between batch-0's publish and its next poll -> the LLC round trip
//    is hidden behind compute instead of idle spinning.
//  - DISTRIBUTED SCORE TAIL: waves 0..4 replicate the aA/cC rings
//    (deterministic, identical inputs -> identical values), each redundantly
//    k-reduces pm, computes ONE score j=q (1 exp + 1 shfl-chain vs wave-0's
//    former 5+5), and publishes its own tagged word right after barrier C.
//    Publishes land earlier and in parallel; poll is all-40-words.
//  - bt pipelined one step deeper (row t+2 issued at step t) so score inputs
//    are register-resident at the tail.
// Kept: tagged 8B words (store IS the publication), wave-0-only poll,
// wave-local ds_read_b128 matvec (no cross-wave barrier B), 2 barriers/step.
// Slot safety: tag t+2 overwrites slot (t+1)&1 (holding tag t) only after our
// step-t poll passed => all siblings published tag t+1 => their tag-t reads
// (their step t-1, pre-publish) completed.

#define BB 32
#define SS 512
#define DD 512
#define NS 5

#define A_ELEMS    ((size_t)BB * SS * DD)            // 32 MB
#define EXCH_U64_PER_B 128                           // 2 slots x 64 (40 used)
#define EXCH_OFF   (A_ELEMS * 4)
#define EXCH_BYTES ((size_t)BB * EXCH_U64_PER_B * 8) // 32 KB
#define WS_NEED    (EXCH_OFF + EXCH_BYTES)

typedef __attribute__((ext_vector_type(4))) float f32x4;

// ---------------- Phase 1: A = H@W1, B2 = H@W2 (fp32) ----------------
__global__ void __launch_bounds__(256) th_phase1(
    const float* __restrict__ H, const float* __restrict__ W1,
    const float* __restrict__ W2, float* __restrict__ A, float* __restrict__ B2) {
  const int tid = threadIdx.x;
  const int mt = blockIdx.x >> 3;
  const int nt = blockIdx.x & 7;
  const int m0 = mt << 6, n0 = nt << 6;
  __shared__ float Ht[64][20];
  __shared__ float Wt1[16][64];
  __shared__ float Wt2[16][64];
  const int tx = tid & 15, ty = tid >> 4;
  const int sr = tid >> 2, sk = (tid & 3) << 2;
  const int wr = tid >> 4, wn = (tid & 15) << 2;
  float a1[4][4] = {{0.f}}, a2[4][4] = {{0.f}};

  for (int k0 = 0; k0 < DD; k0 += 16) {
    float4 hv  = *(const float4*)&H[(size_t)(m0 + sr) * DD + k0 + sk];
    float4 w1v = *(const float4*)&W1[(size_t)(k0 + wr) * DD + n0 + wn];
    float4 w2v = *(const float4*)&W2[(size_t)(k0 + wr) * DD + n0 + wn];
    *(float4*)&Ht[sr][sk]  = hv;
    *(float4*)&Wt1[wr][wn] = w1v;
    *(float4*)&Wt2[wr][wn] = w2v;
    __syncthreads();
#pragma unroll
    for (int kq = 0; kq < 16; kq += 4) {
      float hs[4][4];
#pragma unroll
      for (int i = 0; i < 4; ++i) {
        float4 h4 = *(const float4*)&Ht[ty * 4 + i][kq];
        hs[i][0] = h4.x; hs[i][1] = h4.y; hs[i][2] = h4.z; hs[i][3] = h4.w;
      }
#pragma unroll
      for (int kk = 0; kk < 4; ++kk) {
        float4 w1f = *(const float4*)&Wt1[kq + kk][tx * 4];
        float4 w2f = *(const float4*)&Wt2[kq + kk][tx * 4];
#pragma unroll
        for (int i = 0; i < 4; ++i) {
          float h = hs[i][kk];
          a1[i][0] = fmaf(h, w1f.x, a1[i][0]);
          a1[i][1] = fmaf(h, w1f.y, a1[i][1]);
          a1[i][2] = fmaf(h, w1f.z, a1[i][2]);
          a1[i][3] = fmaf(h, w1f.w, a1[i][3]);
          a2[i][0] = fmaf(h, w2f.x, a2[i][0]);
          a2[i][1] = fmaf(h, w2f.y, a2[i][1]);
          a2[i][2] = fmaf(h, w2f.z, a2[i][2]);
          a2[i][3] = fmaf(h, w2f.w, a2[i][3]);
        }
      }
    }
    __syncthreads();
  }
#pragma unroll
  for (int i = 0; i < 4; ++i) {
    float4 o1 = make_float4(a1[i][0], a1[i][1], a1[i][2], a1[i][3]);
    float4 o2 = make_float4(a2[i][0], a2[i][1], a2[i][2], a2[i][3]);
    size_t off = (size_t)(m0 + ty * 4 + i) * DD + n0 + tx * 4;
    *(float4*)&A[off]  = o1;
    *(float4*)&B2[off] = o2;
  }
}

// ---------------- Phase 2: one recurrence step for one batch ----------------
template <int P>
__device__ __forceinline__ void step_one(
    int t, int tid, int q, int ln, int col, int g,
    const float* __restrict__ Hb, const float* __restrict__ Ab,
    float* __restrict__ Op, unsigned long long* __restrict__ eb,
    const float (&wa)[64], float v_col,
    float (&aA)[NS], float (&cC)[NS], float (&tl)[NS],
    float& h_cur, float& bt_cur,
    float* tlds_b, float* pm_b, float* wl_b) {
  const bool pub = (t + 1 < SS);

  // ---- prefetches (issued first; consumed at the tail / next step)
  float aN_v = 0.f, bt_nxt = 0.f;
  if (q < NS) {
    aN_v = Ab[(size_t)t * DD + col];                  // A row t
    if (t + 2 < SS) bt_nxt = Op[(size_t)(t + 2) * DD + col];  // B2 row t+2
  }
  float h_nxt = 0.f;
  if (pub) h_nxt = Hb[(size_t)(t + 1) * DD + tid];

  // ---- wave 0: poll 40 tagged words (slot t&1, tag t+1), softmax -> wl
  if (q == 0 && t >= 1) {
    const unsigned long long* wsl = eb + (size_t)(t & 1) * 64;
    float pv = 0.f;
    if (ln < 40) {
      unsigned long long w;
      do {
        w = __hip_atomic_load(&wsl[ln], __ATOMIC_RELAXED,
                              __HIP_MEMORY_SCOPE_AGENT);
      } while ((unsigned)(w >> 32) != (unsigned)(t + 1));
      pv = __uint_as_float((unsigned)w);
    }
    pv += __shfl_xor(pv, 1, 64);
    pv += __shfl_xor(pv, 2, 64);
    pv += __shfl_xor(pv, 4, 64);     // each 8-group holds its j-total
    float sc0 = __shfl(pv, 0, 64);
    float sc1 = __shfl(pv, 8, 64);
    float sc2 = __shfl(pv, 16, 64);
    float sc3 = __shfl(pv, 24, 64);
    float sc4 = __shfl(pv, 32, 64);
    float mx = fmaxf(fmaxf(fmaxf(sc0, sc1), fmaxf(sc2, sc3)), sc4);
    float e0 = __expf(sc0 - mx), e1 = __expf(sc1 - mx);
    float e2 = __expf(sc2 - mx), e3 = __expf(sc3 - mx);
    float e4 = __expf(sc4 - mx);
    float inv = 1.0f / (e0 + e1 + e2 + e3 + e4);
    float wv = e0 * inv;
    wv = (ln == 1) ? e1 * inv : wv;
    wv = (ln == 2) ? e2 * inv : wv;
    wv = (ln == 3) ? e3 * inv : wv;
    wv = (ln == 4) ? e4 * inv : wv;
    if (ln < NS) wl_b[ln] = wv;
  }
  __syncthreads();                                    // A: weights ready

  // ---- all threads: tilde row (registers + 5 broadcast LDS reads)
  float w0 = wl_b[0], w1 = wl_b[1], w2 = wl_b[2], w3_ = wl_b[3], w4 = wl_b[4];
  float hh = w0 * tl[P % NS];
  hh = fmaf(w1, tl[(P + 1) % NS], hh);
  hh = fmaf(w2, tl[(P + 2) % NS], hh);
  hh = fmaf(w3_, tl[(P + 3) % NS], hh);
  hh = fmaf(w4, tl[(P + 4) % NS], hh);
  float tld = h_cur + fmaxf(hh, 0.f);
  tl[P % NS] = tld;
  tlds_b[tid] = tld;
  if (g == 0) Op[(size_t)t * DD + tid] = tld;  // row t dead (poll passed)
  // wave-local: matvec reads ONLY this wave's own tlds segment
  asm volatile("s_waitcnt lgkmcnt(0)" ::: "memory");

  // ---- matvec: own 64 cols, k in [q*64, q*64+64), wave-uniform reads
  float a0 = 0.f, a1 = 0.f, a2 = 0.f, a3 = 0.f;
  const f32x4* tv = (const f32x4*)&tlds_b[q << 6];
#pragma unroll
  for (int i = 0; i < 16; ++i) {
    f32x4 t4 = tv[i];
    a0 = fmaf(t4.x, wa[4 * i + 0], a0);
    a1 = fmaf(t4.y, wa[4 * i + 1], a1);
    a2 = fmaf(t4.z, wa[4 * i + 2], a2);
    a3 = fmaf(t4.w, wa[4 * i + 3], a3);
  }
  pm_b[tid] = (a0 + a1) + (a2 + a3);
  __syncthreads();                                    // C: pm ready

  // ---- waves 0..4: redundant k-reduce, ring update, score j=q, publish
  if (q < NS) {
    float c = 0.f;
#pragma unroll
    for (int s = 0; s < 8; ++s) c += pm_b[s * 64 + ln];
    aA[P % NS] = aN_v;                                // A row t -> slot t%5
    cC[P % NS] = c;                                   // c row t -> slot t%5
    if (pub) {
      // score j=q for step t+1 uses row t-4+q -> slot (P+1+q)%5 (q uniform)
      float aa = aA[(P + 1) % NS];
      aa = (q == 1) ? aA[(P + 2) % NS] : aa;
      aa = (q == 2) ? aA[(P + 3) % NS] : aa;
      aa = (q == 3) ? aA[(P + 4) % NS] : aa;
      aa = (q == 4) ? aA[P % NS] : aa;
      float cc = cC[(P + 1) % NS];
      cc = (q == 1) ? cC[(P + 2) % NS] : cc;
      cc = (q == 2) ? cC[(P + 3) % NS] : cc;
      cc = (q == 3) ? cC[(P + 4) % NS] : cc;
      cc = (q == 4) ? cC[P % NS] : cc;
      float x = aa + bt_cur + cc;
      float e = __expf(2.0f * x);
      float s = (1.0f - 2.0f / (e + 1.0f)) * v_col;
#pragma unroll
      for (int off = 32; off >= 1; off >>= 1) s += __shfl_xor(s, off, 64);
      if (ln == 0)
        __hip_atomic_store(&eb[(size_t)((t + 1) & 1) * 64 + q * 8 + g],
            (unsigned long long)__float_as_uint(s) |
                ((unsigned long long)(t + 2) << 32),
            __ATOMIC_RELAXED, __HIP_MEMORY_SCOPE_AGENT);
    }
    bt_cur = bt_nxt;
  }
  h_cur = h_nxt;
}

// grid 128: bid = g*16 + blow; WG serves batches blow and blow+16.
// bid%8 = blow%8 -> all 8 siblings of a batch on one XCD (mod-8 rr).
__global__ void __launch_bounds__(512) th_phase2(
    const float* __restrict__ H, const float* __restrict__ v,
    const float* __restrict__ W3, const float* __restrict__ A,
    float* __restrict__ Ob,  // d_out: holds B2, overwritten with tilde rows
    unsigned long long* __restrict__ exch) {
  const int tid = threadIdx.x;
  const int blow = blockIdx.x & 15;
  const int g = blockIdx.x >> 4;     // 0..7: cols [g*64, g*64+64)
  const int q = tid >> 6;            // wave id == k-segment 0..7
  const int ln = tid & 63;
  const int col = (g << 6) + ln;

  __shared__ float tlds[2][DD];
  __shared__ float pm[2][DD];
  __shared__ float wl[2][8];

  // W3 slice in plain VGPRs (shared by both batches): wa[i] = W3[q*64+i][col]
  float wa[64];
#pragma unroll
  for (int i = 0; i < 64; ++i)
    wa[i] = W3[(size_t)(q * 64 + i) * DD + col];

  const int b0 = blow, b1 = blow + 16;
  const float* Hb0 = H + (size_t)b0 * SS * DD;
  const float* Hb1 = H + (size_t)b1 * SS * DD;
  const float* Ab0 = A + (size_t)b0 * SS * DD;
  const float* Ab1 = A + (size_t)b1 * SS * DD;
  float* Op0 = Ob + (size_t)b0 * SS * DD;
  float* Op1 = Ob + (size_t)b1 * SS * DD;
  unsigned long long* eb0 = exch + (size_t)b0 * EXCH_U64_PER_B;
  unsigned long long* eb1 = exch + (size_t)b1 * EXCH_U64_PER_B;

  float v_col = (q < NS) ? v[col] : 0.f;
  float aA0[NS] = {0.f, 0.f, 0.f, 0.f, 0.f}, aA1[NS] = {0.f, 0.f, 0.f, 0.f, 0.f};
  float cC0[NS] = {0.f, 0.f, 0.f, 0.f, 0.f}, cC1[NS] = {0.f, 0.f, 0.f, 0.f, 0.f};
  float tl0[NS] = {0.f, 0.f, 0.f, 0.f, 0.f}, tl1[NS] = {0.f, 0.f, 0.f, 0.f, 0.f};
  float h0 = Hb0[tid], h1 = Hb1[tid];
  float bt0 = 0.f, bt1 = 0.f;
  if (q < NS) {
    bt0 = Op0[DD + col];             // B2 row 1 (scores published at step 0)
    bt1 = Op1[DD + col];
  }
  if (tid < NS) { wl[0][tid] = 0.2f; wl[1][tid] = 0.2f; }  // step-0 weights

#pragma unroll 1
  for (int t5 = 0; t5 < 515; t5 += 5) {
    { const int t = t5 + 0; if (t < SS) {
        step_one<0>(t, tid, q, ln, col, g, Hb0, Ab0, Op0, eb0, wa, v_col,
                    aA0, cC0, tl0, h0, bt0, tlds[0], pm[0], wl[0]);
        step_one<0>(t, tid, q, ln, col, g, Hb1, Ab1, Op1, eb1, wa, v_col,
                    aA1, cC1, tl1, h1, bt1, tlds[1], pm[1], wl[1]); } }
    { const int t = t5 + 1; if (t < SS) {
        step_one<1>(t, tid, q, ln, col, g, Hb0, Ab0, Op0, eb0, wa, v_col,
                    aA0, cC0, tl0, h0, bt0, tlds[0], pm[0], wl[0]);
        step_one<1>(t, tid, q, ln, col, g, Hb1, Ab1, Op1, eb1, wa, v_col,
                    aA1, cC1, tl1, h1, bt1, tlds[1], pm[1], wl[1]); } }
    { const int t = t5 + 2; if (t < SS) {
        step_one<2>(t, tid, q, ln, col, g, Hb0, Ab0, Op0, eb0, wa, v_col,
                    aA0, cC0, tl0, h0, bt0, tlds[0], pm[0], wl[0]);
        step_one<2>(t, tid, q, ln, col, g, Hb1, Ab1, Op1, eb1, wa, v_col,
                    aA1, cC1, tl1, h1, bt1, tlds[1], pm[1], wl[1]); } }
    { const int t = t5 + 3; if (t < SS) {
        step_one<3>(t, tid, q, ln, col, g, Hb0, Ab0, Op0, eb0, wa, v_col,
                    aA0, cC0, tl0, h0, bt0, tlds[0], pm[0], wl[0]);
        step_one<3>(t, tid, q, ln, col, g, Hb1, Ab1, Op1, eb1, wa, v_col,
                    aA1, cC1, tl1, h1, bt1, tlds[1], pm[1], wl[1]); } }
    { const int t = t5 + 4; if (t < SS) {
        step_one<4>(t, tid, q, ln, col, g, Hb0, Ab0, Op0, eb0, wa, v_col,
                    aA0, cC0, tl0, h0, bt0, tlds[0], pm[0], wl[0]);
        step_one<4>(t, tid, q, ln, col, g, Hb1, Ab1, Op1, eb1, wa, v_col,
                    aA1, cC1, tl1, h1, bt1, tlds[1], pm[1], wl[1]); } }
  }
}

extern "C" void kernel_launch(void* const* d_in, const int* in_sizes, int n_in,
                              void* d_out, int out_size, void* d_ws, size_t ws_size,
                              hipStream_t stream) {
  const float* H  = (const float*)d_in[0];
  const float* v  = (const float*)d_in[1];
  const float* W1 = (const float*)d_in[2];
  const float* W2 = (const float*)d_in[3];
  const float* W3 = (const float*)d_in[4];
  float* out = (float*)d_out;

  if (ws_size < WS_NEED) return;

  float* A = (float*)d_ws;
  unsigned long long* exch = (unsigned long long*)((char*)d_ws + EXCH_OFF);

  (void)hipMemsetAsync(exch, 0, EXCH_BYTES, stream);
  hipLaunchKernelGGL(th_phase1, dim3(256 * 8), dim3(256), 0, stream,
                     H, W1, W2, A, out);
  hipLaunchKernelGGL(th_phase2, dim3(128), dim3(512), 0, stream,
                     H, v, W3, A, out, exch);
}

// Round 5
// 1249.042 us; speedup vs baseline: 1.7232x; 1.7232x over previous
//
#include <hip/hip_runtime.h>

// TruncatedHistoryAttn, round 11.
// Phase 1 (unchanged): fp32 tiled GEMM  A = H@W1 (-> ws), B2 = H@W2 (-> d_out).
// Phase 2 = round-9 skeleton (grid 256, wave-0 poll, 2 barriers/step) +
// EARLY DISTRIBUTED PUBLISH (round-10 post-mortem: interleave halved
// parallelism for a sub-2x per-step gain; this round keeps 256 WGs):
//  - Scores j=0..3 for step t+1 depend only on rows t-4..t-1 -> computable at
//    step-t START. Waves 1..4 (replica rings) each compute ONE score and
//    publish it at step start, in parallel with wave 0's poll. These words
//    arrive a full step early -> consumers' poll finds them instantly.
//  - Wave-0 tail shrinks to: k-reduce + 1 exp + 1 shfl-chain + 1 publish
//    (j=4 only, needs this step's matvec). Exposed chain per step is now
//    (short tail -> LLC -> detect of 8 j=4 words) instead of
//    (long 5-score tail -> LLC -> detect of 40 words).
//  - Wave 0 substitutes own j=4 from register (s4_prev); own j=0..3 come from
//    the exchange (published a step earlier, already visible).
// Slot safety (2-slot parity still sound with early publish): our step-t poll
// passing proves all siblings' step-(t-1) polls passed (their j=4 tag-t+1
// words are tail-published AFTER their poll), so overwriting tag-t words with
// tag-t+2 at step-t start cannot strand a lagging poller.

#define BB 32
#define SS 512
#define DD 512
#define NS 5

#define A_ELEMS    ((size_t)BB * SS * DD)            // 32 MB
#define EXCH_U64_PER_B 128                           // 2 slots x 64 (40 used)
#define EXCH_OFF   (A_ELEMS * 4)
#define EXCH_BYTES ((size_t)BB * EXCH_U64_PER_B * 8) // 32 KB
#define WS_NEED    (EXCH_OFF + EXCH_BYTES)

typedef __attribute__((ext_vector_type(4))) float f32x4;

// ---------------- Phase 1: A = H@W1, B2 = H@W2 (fp32) ----------------
__global__ void __launch_bounds__(256) th_phase1(
    const float* __restrict__ H, const float* __restrict__ W1,
    const float* __restrict__ W2, float* __restrict__ A, float* __restrict__ B2) {
  const int tid = threadIdx.x;
  const int mt = blockIdx.x >> 3;
  const int nt = blockIdx.x & 7;
  const int m0 = mt << 6, n0 = nt << 6;
  __shared__ float Ht[64][20];
  __shared__ float Wt1[16][64];
  __shared__ float Wt2[16][64];
  const int tx = tid & 15, ty = tid >> 4;
  const int sr = tid >> 2, sk = (tid & 3) << 2;
  const int wr = tid >> 4, wn = (tid & 15) << 2;
  float a1[4][4] = {{0.f}}, a2[4][4] = {{0.f}};

  for (int k0 = 0; k0 < DD; k0 += 16) {
    float4 hv  = *(const float4*)&H[(size_t)(m0 + sr) * DD + k0 + sk];
    float4 w1v = *(const float4*)&W1[(size_t)(k0 + wr) * DD + n0 + wn];
    float4 w2v = *(const float4*)&W2[(size_t)(k0 + wr) * DD + n0 + wn];
    *(float4*)&Ht[sr][sk]  = hv;
    *(float4*)&Wt1[wr][wn] = w1v;
    *(float4*)&Wt2[wr][wn] = w2v;
    __syncthreads();
#pragma unroll
    for (int kq = 0; kq < 16; kq += 4) {
      float hs[4][4];
#pragma unroll
      for (int i = 0; i < 4; ++i) {
        float4 h4 = *(const float4*)&Ht[ty * 4 + i][kq];
        hs[i][0] = h4.x; hs[i][1] = h4.y; hs[i][2] = h4.z; hs[i][3] = h4.w;
      }
#pragma unroll
      for (int kk = 0; kk < 4; ++kk) {
        float4 w1f = *(const float4*)&Wt1[kq + kk][tx * 4];
        float4 w2f = *(const float4*)&Wt2[kq + kk][tx * 4];
#pragma unroll
        for (int i = 0; i < 4; ++i) {
          float h = hs[i][kk];
          a1[i][0] = fmaf(h, w1f.x, a1[i][0]);
          a1[i][1] = fmaf(h, w1f.y, a1[i][1]);
          a1[i][2] = fmaf(h, w1f.z, a1[i][2]);
          a1[i][3] = fmaf(h, w1f.w, a1[i][3]);
          a2[i][0] = fmaf(h, w2f.x, a2[i][0]);
          a2[i][1] = fmaf(h, w2f.y, a2[i][1]);
          a2[i][2] = fmaf(h, w2f.z, a2[i][2]);
          a2[i][3] = fmaf(h, w2f.w, a2[i][3]);
        }
      }
    }
    __syncthreads();
  }
#pragma unroll
  for (int i = 0; i < 4; ++i) {
    float4 o1 = make_float4(a1[i][0], a1[i][1], a1[i][2], a1[i][3]);
    float4 o2 = make_float4(a2[i][0], a2[i][1], a2[i][2], a2[i][3]);
    size_t off = (size_t)(m0 + ty * 4 + i) * DD + n0 + tx * 4;
    *(float4*)&A[off]  = o1;
    *(float4*)&B2[off] = o2;
  }
}

// ---------------- Phase 2: the recurrence ----------------
// grid 256 = 8 WGs/batch; bid = g*32+b -> all siblings on one XCD (mod-8 rr).
__global__ void __launch_bounds__(512) th_phase2(
    const float* __restrict__ H, const float* __restrict__ v,
    const float* __restrict__ W3, const float* __restrict__ A,
    float* __restrict__ Ob,  // d_out: holds B2, overwritten with tilde rows
    unsigned long long* __restrict__ exch) {
  const int tid = threadIdx.x;
  const int b = blockIdx.x & 31;
  const int g = blockIdx.x >> 5;     // 0..7: cols [g*64, g*64+64)
  const int q = tid >> 6;            // wave id == k-segment 0..7
  const int ln = tid & 63;
  const int col = (g << 6) + ln;

  __shared__ float tlds[DD];         // tilde_t row
  __shared__ float pm[DD];           // matvec k-segment partials
  __shared__ float wl[8];            // softmax weights broadcast

  // W3 slice in plain VGPRs: wa[i] = W3[q*64+i][col]
  float wa[64];
#pragma unroll
  for (int i = 0; i < 64; ++i)
    wa[i] = W3[(size_t)(q * 64 + i) * DD + col];

  const float* Hb = H + (size_t)b * SS * DD;
  const float* Ab = A + (size_t)b * SS * DD;
  float* Op = Ob + (size_t)b * SS * DD;
  unsigned long long* eb = exch + (size_t)b * EXCH_U64_PER_B;

  // waves 0..4: replica rings over this WG's 64 cols (row s in slot s%5)
  float v_col = (q < NS) ? v[col] : 0.f;
  float aA[NS] = {0.f, 0.f, 0.f, 0.f, 0.f};
  float cC[NS] = {0.f, 0.f, 0.f, 0.f, 0.f};
  float tl[NS] = {0.f, 0.f, 0.f, 0.f, 0.f};
  float s4_prev = 0.f;               // wave 0: own j=4 score (self-substitute)
  float h_cur = Hb[tid];
  float btB = (q < NS) ? Op[DD + col] : 0.f;  // B2 row t+1 (init: row 1)

  if (tid < NS) wl[tid] = 0.2f;      // step-0 weights: exactly uniform

#pragma unroll 1
  for (int t5 = 0; t5 < 515; t5 += 5) {
#pragma unroll
    for (int p = 0; p < NS; ++p) {
      const int t = t5 + p;
      if (t < SS) {
        const bool pub = (t + 1 < SS);

        // ---- prefetches
        float aN_v = 0.f, bt2 = 0.f;
        if (q < NS) {
          aN_v = Ab[(size_t)t * DD + col];                  // A row t
          if (t + 2 < SS) bt2 = Op[(size_t)(t + 2) * DD + col];  // B2 row t+2
        }
        float h_nxt = 0.f;
        if (pub) h_nxt = Hb[(size_t)(t + 1) * DD + tid];

        // ---- waves 1..4: EARLY publish of score j=q-1 for step t+1
        // (rows t-4..t-1, all in rings since step t-1's tail; bt = row t+1)
        if (q >= 1 && q < NS && pub) {
          float aa = aA[(p + 1) % NS];
          aa = (q == 2) ? aA[(p + 2) % NS] : aa;
          aa = (q == 3) ? aA[(p + 3) % NS] : aa;
          aa = (q == 4) ? aA[(p + 4) % NS] : aa;
          float cc = cC[(p + 1) % NS];
          cc = (q == 2) ? cC[(p + 2) % NS] : cc;
          cc = (q == 3) ? cC[(p + 3) % NS] : cc;
          cc = (q == 4) ? cC[(p + 4) % NS] : cc;
          float x = aa + btB + cc;
          float e = __expf(2.0f * x);
          float s = (1.0f - 2.0f / (e + 1.0f)) * v_col;
#pragma unroll
          for (int off = 32; off >= 1; off >>= 1) s += __shfl_xor(s, off, 64);
          if (ln == 0)
            __hip_atomic_store(&eb[(size_t)((t + 1) & 1) * 64 + (q - 1) * 8 + g],
                (unsigned long long)__float_as_uint(s) |
                    ((unsigned long long)(t + 2) << 32),
                __ATOMIC_RELAXED, __HIP_MEMORY_SCOPE_AGENT);
        }

        // ---- wave 0: poll tagged words (slot t&1, tag t+1) -> softmax -> wl
        // 32 j=0..3 words arrived a step early; only 7 foreign j=4 are fresh;
        // own j=4 substituted from s4_prev.
        if (q == 0 && t >= 1) {
          const unsigned long long* wsl = eb + (size_t)(t & 1) * 64;
          float pv = 0.f;
          if (ln < 40) {
            if (!((ln >> 3) == 4 && (ln & 7) == g)) {
              unsigned long long w;
              do {
                w = __hip_atomic_load(&wsl[ln], __ATOMIC_RELAXED,
                                      __HIP_MEMORY_SCOPE_AGENT);
              } while ((unsigned)(w >> 32) != (unsigned)(t + 1));
              pv = __uint_as_float((unsigned)w);
            } else {
              pv = s4_prev;
            }
          }
          pv += __shfl_xor(pv, 1, 64);
          pv += __shfl_xor(pv, 2, 64);
          pv += __shfl_xor(pv, 4, 64);   // each 8-group holds its j-total
          float sc0 = __shfl(pv, 0, 64);
          float sc1 = __shfl(pv, 8, 64);
          float sc2 = __shfl(pv, 16, 64);
          float sc3 = __shfl(pv, 24, 64);
          float sc4 = __shfl(pv, 32, 64);
          float mx = fmaxf(fmaxf(fmaxf(sc0, sc1), fmaxf(sc2, sc3)), sc4);
          float e0 = __expf(sc0 - mx), e1 = __expf(sc1 - mx);
          float e2 = __expf(sc2 - mx), e3 = __expf(sc3 - mx);
          float e4 = __expf(sc4 - mx);
          float inv = 1.0f / (e0 + e1 + e2 + e3 + e4);
          float wv = e0 * inv;
          wv = (ln == 1) ? e1 * inv : wv;
          wv = (ln == 2) ? e2 * inv : wv;
          wv = (ln == 3) ? e3 * inv : wv;
          wv = (ln == 4) ? e4 * inv : wv;
          if (ln < NS) wl[ln] = wv;
        }
        __syncthreads();                           // A: weights ready

        // ---- all threads: tilde row (registers + 5 broadcast LDS reads)
        float w0 = wl[0], w1 = wl[1], w2 = wl[2], w3_ = wl[3], w4 = wl[4];
        float hh = w0 * tl[p];
        hh = fmaf(w1, tl[(p + 1) % NS], hh);
        hh = fmaf(w2, tl[(p + 2) % NS], hh);
        hh = fmaf(w3_, tl[(p + 3) % NS], hh);
        hh = fmaf(w4, tl[(p + 4) % NS], hh);
        float tld = h_cur + fmaxf(hh, 0.f);
        tl[p] = tld;
        tlds[tid] = tld;
        if (g == 0) Op[(size_t)t * DD + tid] = tld;  // row t dead (poll passed)
        // wave-local: matvec reads ONLY this wave's own tlds segment
        asm volatile("s_waitcnt lgkmcnt(0)" ::: "memory");

        // ---- matvec: own 64 cols, k in [q*64, q*64+64), wave-uniform reads
        float a0 = 0.f, a1 = 0.f, a2 = 0.f, a3 = 0.f;
        const f32x4* tv = (const f32x4*)&tlds[q << 6];
#pragma unroll
        for (int i = 0; i < 16; ++i) {
          f32x4 t4 = tv[i];
          a0 = fmaf(t4.x, wa[4 * i + 0], a0);
          a1 = fmaf(t4.y, wa[4 * i + 1], a1);
          a2 = fmaf(t4.z, wa[4 * i + 2], a2);
          a3 = fmaf(t4.w, wa[4 * i + 3], a3);
        }
        pm[tid] = (a0 + a1) + (a2 + a3);
        __syncthreads();                           // C: pm ready

        // ---- waves 0..4: k-reduce + ring update; wave 0: score j=4, publish
        if (q < NS) {
          float c = 0.f;
#pragma unroll
          for (int s = 0; s < 8; ++s) c += pm[s * 64 + ln];
          aA[p] = aN_v;                            // A row t -> slot t%5
          cC[p] = c;                               // c row t -> slot t%5
          if (q == 0 && pub) {
            float x = aN_v + btB + c;              // row t, bt = row t+1
            float e = __expf(2.0f * x);
            float s4 = (1.0f - 2.0f / (e + 1.0f)) * v_col;
#pragma unroll
            for (int off = 32; off >= 1; off >>= 1) s4 += __shfl_xor(s4, off, 64);
            if (ln == 0)
              __hip_atomic_store(&eb[(size_t)((t + 1) & 1) * 64 + 32 + g],
                  (unsigned long long)__float_as_uint(s4) |
                      ((unsigned long long)(t + 2) << 32),
                  __ATOMIC_RELAXED, __HIP_MEMORY_SCOPE_AGENT);
            s4_prev = s4;
          }
          btB = bt2;
        }
        h_cur = h_nxt;
      }
    }
  }
}

extern "C" void kernel_launch(void* const* d_in, const int* in_sizes, int n_in,
                              void* d_out, int out_size, void* d_ws, size_t ws_size,
                              hipStream_t stream) {
  const float* H  = (const float*)d_in[0];
  const float* v  = (const float*)d_in[1];
  const float* W1 = (const float*)d_in[2];
  const float* W2 = (const float*)d_in[3];
  const float* W3 = (const float*)d_in[4];
  float* out = (float*)d_out;

  if (ws_size < WS_NEED) return;

  float* A = (float*)d_ws;
  unsigned long long* exch = (unsigned long long*)((char*)d_ws + EXCH_OFF);

  (void)hipMemsetAsync(exch, 0, EXCH_BYTES, stream);
  hipLaunchKernelGGL(th_phase1, dim3(256 * 8), dim3(256), 0, stream,
                     H, W1, W2, A, out);
  hipLaunchKernelGGL(th_phase2, dim3(BB * 8), dim3(512), 0, stream,
                     H, v, W3, A, out, exch);
}